// Round 7
// baseline (175.115 us; speedup 1.0000x reference)
//
#include <hip/hip_runtime.h>

#define NNODES 10000
#define NEDGES 160000
#define MUL 16
#define EMB 64
#define HID 128

#define RS128 0.08838834764831845f           // 1/sqrt(128)
#define SC3   (0.08838834764831845f * 0.25f) // 1/sqrt(128) * 1/sqrt(MUL)

typedef __attribute__((ext_vector_type(8))) _Float16 half8;
typedef __attribute__((ext_vector_type(4))) _Float16 half4;
typedef __attribute__((ext_vector_type(4))) float f32x4;

#define MF(A, B, C) __builtin_amdgcn_mfma_f32_16x16x32_f16((A), (B), (C), 0, 0, 0)

// ---------------------------------------------------------------------------
// Self-connection: initializes every element of out (runs first).
// ---------------------------------------------------------------------------
__global__ __launch_bounds__(256) void selfconn_kernel(
    const float* __restrict__ node_feat,
    const float* __restrict__ sc_w0,
    const float* __restrict__ sc_w1,
    float* __restrict__ out)
{
    const int tid = threadIdx.x;
    const int nl = tid >> 4;
    const int wp = tid & 15;
    const int n  = blockIdx.x * 16 + nl;

    __shared__ float nf[16][64];
    __shared__ float w0s[16][16];
    __shared__ float w1s[16][16];

    ((float4*)nf)[tid] = ((const float4*)(node_feat + (size_t)blockIdx.x * 16 * 64))[tid];
    if (tid < 64)       ((float4*)w0s)[tid]      = ((const float4*)sc_w0)[tid];
    else if (tid < 128) ((float4*)w1s)[tid - 64] = ((const float4*)sc_w1)[tid - 64];
    __syncthreads();

    float o0 = 0.f, o1x = 0.f, o1y = 0.f, o1z = 0.f;
#pragma unroll
    for (int u = 0; u < 16; ++u) {
        o0 += nf[nl][u] * w0s[u][wp];
        const float wv = w1s[u][wp];
        o1x += nf[nl][16 + u * 3 + 0] * wv;
        o1y += nf[nl][16 + u * 3 + 1] * wv;
        o1z += nf[nl][16 + u * 3 + 2] * wv;
    }
    float* op = out + (size_t)n * 64;
    op[wp]              = o0  * 0.25f;
    op[16 + wp * 3 + 0] = o1x * 0.25f;
    op[16 + wp * 3 + 1] = o1y * 0.25f;
    op[16 + wp * 3 + 2] = o1z * 0.25f;
}

// ---------------------------------------------------------------------------
// Prep: pack fc weights as fp16 in 16x16x32 MFMA B-fragment order, scales folded.
// half-index = ((nt*KS + ks)*64 + lane)*8 + j ; B[k=ks*32+(lane>>4)*8+j][n=nt*16+(lane&15)]
//   w1p: 8 nt x 2 ks  -> [0, 8192)
//   w2p: 8 nt x 4 ks  -> [8192, 24576)
//   w3p: 80 nt x 4 ks -> [24576, 188416)
// ---------------------------------------------------------------------------
__global__ __launch_bounds__(256) void prep_kernel(
    const float* __restrict__ w1,
    const float* __restrict__ w2,
    const float* __restrict__ w3,
    _Float16* __restrict__ wp)
{
    int idx = blockIdx.x * 256 + threadIdx.x;
    if (idx < 8192) {
        int j = idx & 7, lane = (idx >> 3) & 63, ks = (idx >> 9) & 1, nt = idx >> 10;
        int k = ks * 32 + (lane >> 4) * 8 + j;
        int n = nt * 16 + (lane & 15);
        wp[idx] = (_Float16)(w1[k * HID + n] * 0.125f);
    } else if (idx < 24576) {
        int t = idx - 8192;
        int j = t & 7, lane = (t >> 3) & 63, ks = (t >> 9) & 3, nt = t >> 11;
        int k = ks * 32 + (lane >> 4) * 8 + j;
        int n = nt * 16 + (lane & 15);
        wp[idx] = (_Float16)(w2[k * HID + n] * RS128);
    } else if (idx < 188416) {
        int t = idx - 24576;
        int j = t & 7, lane = (t >> 3) & 63, ks = (t >> 9) & 3, nt = t >> 11;
        int k = ks * 32 + (lane >> 4) * 8 + j;
        int n = nt * 16 + (lane & 15);
        wp[idx] = (_Float16)(w3[k * 1280 + n] * SC3);
    }
}

// ---------------------------------------------------------------------------
// LDS layout (bytes), 64 edges per block:
//   [0,8192)       ee (fp16, swizzled 128B rows, 64 rows)
//   [8192,25600)   H: xg f32 (64 rows padded to 68 fl) -> h1/h2 fp16 swz (64x256B)
//   [25600,29952)  sA_T  [16][68] f32 (stride 272B)  x0*y0
//   [29952,34304)  sB_T  [16][68]                    dot/sqrt3
//   [34304,46848)  sXY_T [16][196] (stride 784B)     x0*y1
//   [46848,59392)  sP3_T [16][196]                   x1*y0
//   [59392,71936)  sP4_T [16][196]                   cross/sqrt2
//   [71936,72960)  sEF   [64][4]
//   [72960,73472)  sidx  [128]  (src 0..63, dst 64..127)
//   opart (4 x 64 x 65 f32 = 66560B) aliases [0,66560) after the tile loop.
// ---------------------------------------------------------------------------
#define EE_OFF   0
#define H_OFF    8192
#define SA_OFF   25600
#define SB_OFF   29952
#define SXY_OFF  34304
#define SP3_OFF  46848
#define SP4_OFF  59392
#define SEF_OFF  71936
#define SIDX_OFF 72960
#define SMEM_BYTES 73472
#define OPW 65

__global__ __launch_bounds__(256, 2) void edge_mfma_kernel(
    const int*   __restrict__ ei,
    const float* __restrict__ node_feat,
    const float* __restrict__ edge_feat,
    const float* __restrict__ edge_embed,
    const _Float16* __restrict__ wpk,
    float* __restrict__ out)
{
    __shared__ __align__(16) char smem[SMEM_BYTES];

    const int tid = threadIdx.x;
    const int e0  = blockIdx.x * 64;

    int*   sidxp = (int*)(smem + SIDX_OFF);
    float* sEFp  = (float*)(smem + SEF_OFF);

    // ---- phase 0: indices + edge_feat ----
    if (tid < 64)       sidxp[tid] = ei[e0 + tid];
    else if (tid < 128) sidxp[tid] = ei[NEDGES + e0 + (tid - 64)];
    sEFp[tid] = edge_feat[e0 * 4 + tid];        // 256 floats = 64 edges x 4
    __syncthreads();

    // ---- phase 1: stage edge_embed (fp16, swizzled) + gather node rows ----
    float* xg = (float*)(smem + H_OFF);   // [64][68] f32 (padded rows)
    {
        const float4* eesrc = (const float4*)(edge_embed + (size_t)e0 * EMB);
#pragma unroll
        for (int it = 0; it < 4; ++it) {
            int f = tid + it * 256;       // 0..1023
            int row = f >> 4, c4 = f & 15;
            float4 v = eesrc[f];
            half4 h = { (_Float16)v.x, (_Float16)v.y, (_Float16)v.z, (_Float16)v.w };
            *(half4*)(smem + EE_OFF + row * 128 + ((c4 * 8) ^ ((row & 7) << 4))) = h;

            int src = sidxp[row];
            float4 nv = ((const float4*)(node_feat + (size_t)src * 64))[c4];
            ((float4*)(xg + row * 68))[c4] = nv;
        }
    }
    __syncthreads();

    // ---- phase 2: per-edge t-vectors, transposed + padded (conflict-free) ----
#pragma unroll
    for (int it = 0; it < 4; ++it) {
        int el = (tid >> 4) + it * 16;    // 0..63
        int u  = tid & 15;
        const float* xr = xg + el * 68;
        float x0u = xr[u];
        float xa  = xr[16 + u * 3 + 0];
        float xb  = xr[16 + u * 3 + 1];
        float xc  = xr[16 + u * 3 + 2];
        float y0  = sEFp[el * 4 + 0];
        float y1x = sEFp[el * 4 + 1];
        float y1y = sEFp[el * 4 + 2];
        float y1z = sEFp[el * 4 + 3];
        *(float*)(smem + SA_OFF + u * 272 + el * 4) = x0u * y0;
        *(float*)(smem + SB_OFF + u * 272 + el * 4) =
            (xa * y1x + xb * y1y + xc * y1z) * 0.5773502691896258f;
        float* xy = (float*)(smem + SXY_OFF + u * 784 + el * 12);
        xy[0] = x0u * y1x; xy[1] = x0u * y1y; xy[2] = x0u * y1z;
        float* p3 = (float*)(smem + SP3_OFF + u * 784 + el * 12);
        p3[0] = xa * y0; p3[1] = xb * y0; p3[2] = xc * y0;
        float* p4 = (float*)(smem + SP4_OFF + u * 784 + el * 12);
        p4[0] = (xb * y1z - xc * y1y) * 0.7071067811865476f;
        p4[1] = (xc * y1x - xa * y1z) * 0.7071067811865476f;
        p4[2] = (xa * y1y - xb * y1x) * 0.7071067811865476f;
    }
    __syncthreads();   // xg dead; H region reusable for h1

    const int lane   = tid & 63;
    const int w      = tid >> 6;
    const int aswz   = (lane & 7) << 4;
    const int ako2   = (lane >> 4) * 16;         // byte offset of k-group
    const int ccol   = lane & 15;
    const int crow00 = (lane >> 4) * 4;          // C row base within a 16-tile

    const half8* w1p8 = (const half8*)wpk;
    const half8* w2p8 = (const half8*)(wpk + 8192);
    const half8* w3p8 = (const half8*)(wpk + 24576);

    // ---- GEMM1: h1 = silu(ee @ w1p); wave w owns cols [32w, 32w+32) ----
    {
        half8 a1r[4][2];
#pragma unroll
        for (int ms = 0; ms < 4; ++ms) {
            const int arow = ms * 16 + (lane & 15);
            a1r[ms][0] = *(const half8*)(smem + EE_OFF + arow * 128 + ((ako2     ) ^ aswz));
            a1r[ms][1] = *(const half8*)(smem + EE_OFF + arow * 128 + ((64 + ako2) ^ aswz));
        }
#pragma unroll
        for (int i = 0; i < 2; ++i) {
            const int nt = 2 * w + i;
            const half8* b = w1p8 + (size_t)(nt * 2) * 64 + lane;
            half8 b0 = b[0], b1 = b[64];
            f32x4 c0 = {0,0,0,0}, c1 = {0,0,0,0}, c2 = {0,0,0,0}, c3 = {0,0,0,0};
            c0 = MF(a1r[0][0], b0, c0); c1 = MF(a1r[1][0], b0, c1);
            c2 = MF(a1r[2][0], b0, c2); c3 = MF(a1r[3][0], b0, c3);
            c0 = MF(a1r[0][1], b1, c0); c1 = MF(a1r[1][1], b1, c1);
            c2 = MF(a1r[2][1], b1, c2); c3 = MF(a1r[3][1], b1, c3);
            f32x4 cs[4] = {c0, c1, c2, c3};
#pragma unroll
            for (int ms = 0; ms < 4; ++ms)
#pragma unroll
                for (int r = 0; r < 4; ++r) {
                    int row = ms * 16 + crow00 + r;
                    int col = nt * 16 + ccol;
                    float x = cs[ms][r];
                    float s = x / (1.f + __expf(-x));
                    *(_Float16*)(smem + H_OFF + row * 256 + ((col * 2) ^ ((row & 7) << 4))) = (_Float16)s;
                }
        }
    }
    __syncthreads();

    // ---- GEMM2: h2 = silu(h1 @ w2p), written back into H after a barrier ----
    {
        half8 a2r[4][4];
#pragma unroll
        for (int ms = 0; ms < 4; ++ms) {
            const int arow = ms * 16 + (lane & 15);
#pragma unroll
            for (int ks = 0; ks < 4; ++ks)
                a2r[ms][ks] = *(const half8*)(smem + H_OFF + arow * 256 + ((ks * 64 + ako2) ^ aswz));
        }
        f32x4 cs[2][4];
#pragma unroll
        for (int i = 0; i < 2; ++i) {
            const int nt = 2 * w + i;
            const half8* b = w2p8 + (size_t)(nt * 4) * 64 + lane;
            half8 b0 = b[0], b1 = b[64], b2 = b[128], b3 = b[192];
            f32x4 c0 = {0,0,0,0}, c1 = {0,0,0,0}, c2 = {0,0,0,0}, c3 = {0,0,0,0};
            c0 = MF(a2r[0][0], b0, c0); c1 = MF(a2r[1][0], b0, c1);
            c2 = MF(a2r[2][0], b0, c2); c3 = MF(a2r[3][0], b0, c3);
            c0 = MF(a2r[0][1], b1, c0); c1 = MF(a2r[1][1], b1, c1);
            c2 = MF(a2r[2][1], b1, c2); c3 = MF(a2r[3][1], b1, c3);
            c0 = MF(a2r[0][2], b2, c0); c1 = MF(a2r[1][2], b2, c1);
            c2 = MF(a2r[2][2], b2, c2); c3 = MF(a2r[3][2], b2, c3);
            c0 = MF(a2r[0][3], b3, c0); c1 = MF(a2r[1][3], b3, c1);
            c2 = MF(a2r[2][3], b3, c2); c3 = MF(a2r[3][3], b3, c3);
            cs[i][0] = c0; cs[i][1] = c1; cs[i][2] = c2; cs[i][3] = c3;
        }
        __syncthreads();   // all h1 reads complete before overwrite
#pragma unroll
        for (int i = 0; i < 2; ++i) {
            const int nt = 2 * w + i;
#pragma unroll
            for (int ms = 0; ms < 4; ++ms)
#pragma unroll
                for (int r = 0; r < 4; ++r) {
                    int row = ms * 16 + crow00 + r;
                    int col = nt * 16 + ccol;
                    float x = cs[i][ms][r];
                    float s = x / (1.f + __expf(-x));
                    *(_Float16*)(smem + H_OFF + row * 256 + ((col * 2) ^ ((row & 7) << 4))) = (_Float16)s;
                }
        }
    }
    __syncthreads();

    // ---- GEMM3: wave w covers 20 nt tiles for ALL 64 edges (4 M-subtiles) ----
    half8 a3[4][4];
#pragma unroll
    for (int ms = 0; ms < 4; ++ms) {
        const int arow = ms * 16 + (lane & 15);
#pragma unroll
        for (int ks = 0; ks < 4; ++ks)
            a3[ms][ks] = *(const half8*)(smem + H_OFF + arow * 256 + ((ks * 64 + ako2) ^ aswz));
    }

    float acc0[4][4] = {};
    float acc1[4][4][3] = {};

#define MM16(NT) \
    const half8* bp = w3p8 + (size_t)(NT) * 256 + lane; \
    half8 b0 = bp[0], b1 = bp[64], b2 = bp[128], b3 = bp[192]; \
    f32x4 c0 = {0,0,0,0}, c1 = {0,0,0,0}, c2 = {0,0,0,0}, c3 = {0,0,0,0}; \
    c0 = MF(a3[0][0], b0, c0); c1 = MF(a3[1][0], b0, c1); \
    c2 = MF(a3[2][0], b0, c2); c3 = MF(a3[3][0], b0, c3); \
    c0 = MF(a3[0][1], b1, c0); c1 = MF(a3[1][1], b1, c1); \
    c2 = MF(a3[2][1], b1, c2); c3 = MF(a3[3][1], b1, c3); \
    c0 = MF(a3[0][2], b2, c0); c1 = MF(a3[1][2], b2, c1); \
    c2 = MF(a3[2][2], b2, c2); c3 = MF(a3[3][2], b2, c3); \
    c0 = MF(a3[0][3], b3, c0); c1 = MF(a3[1][3], b3, c1); \
    c2 = MF(a3[2][3], b3, c2); c3 = MF(a3[3][3], b3, c3);

#define EPIT1(CV, MS, TBB) { \
    float4 t = *(const float4*)(TBB); \
    acc0[MS][0] += CV[0] * t.x; acc0[MS][1] += CV[1] * t.y; \
    acc0[MS][2] += CV[2] * t.z; acc0[MS][3] += CV[3] * t.w; }

#define EPIV1(CV, MS, TBB) { \
    float4 q0 = *(const float4*)(TBB); \
    float4 q1 = *(const float4*)((TBB) + 16); \
    float4 q2 = *(const float4*)((TBB) + 32); \
    acc1[MS][0][0] += CV[0]*q0.x; acc1[MS][0][1] += CV[0]*q0.y; acc1[MS][0][2] += CV[0]*q0.z; \
    acc1[MS][1][0] += CV[1]*q0.w; acc1[MS][1][1] += CV[1]*q1.x; acc1[MS][1][2] += CV[1]*q1.y; \
    acc1[MS][2][0] += CV[2]*q1.z; acc1[MS][2][1] += CV[2]*q1.w; acc1[MS][2][2] += CV[2]*q2.x; \
    acc1[MS][3][0] += CV[3]*q2.y; acc1[MS][3][1] += CV[3]*q2.z; acc1[MS][3][2] += CV[3]*q2.w; }

#define TILE_T(NT, U, TOFF) { \
    MM16(NT); \
    const char* tb = smem + (TOFF) + (U) * 272 + crow00 * 4; \
    EPIT1(c0, 0, tb); EPIT1(c1, 1, tb + 64); \
    EPIT1(c2, 2, tb + 128); EPIT1(c3, 3, tb + 192); }

#define TILE_V(NT, U, TOFF) { \
    MM16(NT); \
    const char* tb = smem + (TOFF) + (U) * 784 + crow00 * 12; \
    EPIV1(c0, 0, tb); EPIV1(c1, 1, tb + 192); \
    EPIV1(c2, 2, tb + 384); EPIV1(c3, 3, tb + 576); }

    switch (w) {
    case 0:
#pragma unroll 4
        for (int u = 0; u < 16; ++u) TILE_T(u, u, SA_OFF);
#pragma unroll
        for (int u = 0; u < 4; ++u)  TILE_T(16 + u, u, SB_OFF);
        break;
    case 1:
#pragma unroll 4
        for (int u = 4; u < 16; ++u) TILE_T(16 + u, u, SB_OFF);
#pragma unroll 4
        for (int u = 0; u < 8; ++u)  TILE_V(32 + u, u, SXY_OFF);
        break;
    case 2:
#pragma unroll 4
        for (int u = 8; u < 16; ++u) TILE_V(32 + u, u, SXY_OFF);
#pragma unroll 4
        for (int u = 0; u < 12; ++u) TILE_V(48 + u, u, SP3_OFF);
        break;
    default:
#pragma unroll
        for (int u = 12; u < 16; ++u) TILE_V(48 + u, u, SP3_OFF);
#pragma unroll 4
        for (int u = 0; u < 16; ++u)  TILE_V(64 + u, u, SP4_OFF);
        break;
    }
#undef MM16
#undef EPIT1
#undef EPIV1
#undef TILE_T
#undef TILE_V

    // ---- cross-wave reduce through LDS (opart aliases [0, 66560)) ----
    __syncthreads();   // all h2 / t-array reads done

    {
        float* myop = (float*)smem + w * 64 * OPW;
#pragma unroll
        for (int ms = 0; ms < 4; ++ms)
#pragma unroll
            for (int r = 0; r < 4; ++r) {
                int row = ms * 16 + crow00 + r;
                float* rp = myop + row * OPW;
                rp[ccol]              = acc0[ms][r];
                rp[16 + ccol * 3 + 0] = acc1[ms][r][0];
                rp[16 + ccol * 3 + 1] = acc1[ms][r][1];
                rp[16 + ccol * 3 + 2] = acc1[ms][r][2];
            }
    }
    __syncthreads();

    {
        const float* opf = (const float*)smem;
        const int rloc = lane >> 4;
#pragma unroll
        for (int rr = 0; rr < 4; ++rr) {
            int row = w * 16 + rr * 4 + rloc;
            int dst = sidxp[64 + row];
            float* op = out + (size_t)dst * 64;
            float v = opf[row * OPW + ccol]         + opf[4160 + row * OPW + ccol]
                    + opf[8320 + row * OPW + ccol]  + opf[12480 + row * OPW + ccol];
            atomicAdd(op + ccol, v);
#pragma unroll
            for (int d = 0; d < 3; ++d) {
                int cc = 16 + ccol * 3 + d;
                float v1 = opf[row * OPW + cc]         + opf[4160 + row * OPW + cc]
                         + opf[8320 + row * OPW + cc]  + opf[12480 + row * OPW + cc];
                atomicAdd(op + cc, v1);
            }
        }
    }
}

extern "C" void kernel_launch(void* const* d_in, const int* in_sizes, int n_in,
                              void* d_out, int out_size, void* d_ws, size_t ws_size,
                              hipStream_t stream) {
    const int*   ei         = (const int*)  d_in[0];
    const float* node_feat  = (const float*)d_in[1];
    const float* edge_feat  = (const float*)d_in[2];
    const float* edge_embed = (const float*)d_in[3];
    const float* fc_w1      = (const float*)d_in[4];
    const float* fc_w2      = (const float*)d_in[5];
    const float* fc_w3      = (const float*)d_in[6];
    const float* sc_w0      = (const float*)d_in[7];
    const float* sc_w1      = (const float*)d_in[8];
    float* out = (float*)d_out;
    _Float16* wpk = (_Float16*)d_ws;   // 188416 halves = 368 KB

    prep_kernel<<<736, 256, 0, stream>>>(fc_w1, fc_w2, fc_w3, wpk);
    selfconn_kernel<<<NNODES / 16, 256, 0, stream>>>(node_feat, sc_w0, sc_w1, out);
    edge_mfma_kernel<<<NEDGES / 64, 256, 0, stream>>>(ei, node_feat, edge_feat, edge_embed,
                                                      wpk, out);
}